// Round 18
// baseline (214.582 us; speedup 1.0000x reference)
//
#include <hip/hip_runtime.h>
#include <hip/hip_bf16.h>
#include <stdint.h>

#define DIN   4096
#define DOUT  4096
#define MTOT  8192

#define BK    64
#define NKT   (DIN / BK)   // 64 K-tiles

typedef int i32x4 __attribute__((ext_vector_type(4)));

__device__ __forceinline__ void glds16(const void* g, void* l) {
  __builtin_amdgcn_global_load_lds(
      (__attribute__((address_space(1))) void*)g,
      (__attribute__((address_space(3))) void*)l, 16, 0, 0);
}

// ---------------------------------------------------------------------------
// Fused prep kernel (one launch, 12288 blocks):
//   blocks [0, DOUT):        per-row alpha (fp64) + ternary quantize W -> i8
//   blocks [DOUT, DOUT+MTOT): per-row max + quantize X -> i8, XS[row]
// ---------------------------------------------------------------------------
__global__ __launch_bounds__(256) void quant_fused(
    const float* __restrict__ W, int8_t* __restrict__ QW,
    const float* __restrict__ X, int8_t* __restrict__ XQ,
    float* __restrict__ XS) {
  const int t = threadIdx.x;

  if (blockIdx.x < DOUT) {
    const int row = blockIdx.x;
    const float* wr = W + (size_t)row * DIN;

    float4 v[4];
    double s = 0.0;
#pragma unroll
    for (int j = 0; j < 4; ++j) {
      v[j] = reinterpret_cast<const float4*>(wr)[j * 256 + t];
      s += (double)fabsf(v[j].x) + (double)fabsf(v[j].y) +
           (double)fabsf(v[j].z) + (double)fabsf(v[j].w);
    }
#pragma unroll
    for (int off = 32; off > 0; off >>= 1) s += __shfl_down(s, off, 64);

    __shared__ double ssum[4];
    __shared__ float salpha;
    if ((t & 63) == 0) ssum[t >> 6] = s;
    __syncthreads();
    if (t == 0)
      salpha = (float)((ssum[0] + ssum[1] + ssum[2] + ssum[3]) / (double)DIN);
    __syncthreads();
    const float alpha = salpha;

    int* qo = reinterpret_cast<int*>(QW + (size_t)row * DIN);
#pragma unroll
    for (int j = 0; j < 4; ++j) {
      int q0 = v[j].x > alpha ? 1 : (v[j].x < -alpha ? -1 : 0);
      int q1 = v[j].y > alpha ? 1 : (v[j].y < -alpha ? -1 : 0);
      int q2 = v[j].z > alpha ? 1 : (v[j].z < -alpha ? -1 : 0);
      int q3 = v[j].w > alpha ? 1 : (v[j].w < -alpha ? -1 : 0);
      qo[j * 256 + t] =
          (q0 & 0xff) | ((q1 & 0xff) << 8) | ((q2 & 0xff) << 16) | ((q3 & 0xff) << 24);
    }
  } else {
    const int row = blockIdx.x - DOUT;
    const float* xr = X + (size_t)row * DIN;

    float4 v[4];
    float mx = 0.f;
#pragma unroll
    for (int j = 0; j < 4; ++j) {
      v[j] = reinterpret_cast<const float4*>(xr)[j * 256 + t];
      mx = fmaxf(mx, fmaxf(fmaxf(fabsf(v[j].x), fabsf(v[j].y)),
                           fmaxf(fabsf(v[j].z), fabsf(v[j].w))));
    }
#pragma unroll
    for (int off = 32; off > 0; off >>= 1) mx = fmaxf(mx, __shfl_down(mx, off, 64));

    __shared__ float smax[4];
    __shared__ float sinv, ssc;
    if ((t & 63) == 0) smax[t >> 6] = mx;
    __syncthreads();
    if (t == 0) {
      float rm = fmaxf(fmaxf(smax[0], smax[1]), fmaxf(smax[2], smax[3]));
      sinv = rm > 0.f ? 127.f / rm : 0.f;
      ssc  = rm > 0.f ? rm / 127.f : 0.f;
    }
    __syncthreads();
    const float inv = sinv;
    if (t == 0) XS[row] = ssc;

    int* qo = reinterpret_cast<int*>(XQ + (size_t)row * DIN);
#pragma unroll
    for (int j = 0; j < 4; ++j) {
      int q0 = (int)rintf(v[j].x * inv);
      int q1 = (int)rintf(v[j].y * inv);
      int q2 = (int)rintf(v[j].z * inv);
      int q3 = (int)rintf(v[j].w * inv);
      qo[j * 256 + t] =
          (q0 & 0xff) | ((q1 & 0xff) << 8) | ((q2 & 0xff) << 16) | ((q3 & 0xff) << 24);
    }
  }
}

// ---------------------------------------------------------------------------
// GEMM kernel, round-18: ONE window per K-tile (window-count trend: 8->4
// = +3.5%, 4->2 = +6%), enabled by 4-deep LDS buffering on BOTH operands.
//
// Geometry: r16's (1024 thr = 16 waves 4Mx4N, wave 64x64, 64 AGPR acc).
// LDS: As[4] + Bs[4] x 16 KB = 128 KB/block (1 block/CU, as before: 16
// waves is a full CU anyway).
//
// Per tile U (ab = U&3, literal per unrolled call):
//   READ a[4]+b[4] (8 ds_read, swizzled, conflict-free);
//   ISSUE A(U+2)->As[(U+2)&3]; ISSUE B(U+2)->Bs[(U+2)&3];
//   MMA16 (consumes this window's reads);
//   vmcnt(2|0); BAR
//
// Overwrite audit: As/Bs[(U+2)&3]'s last LDS reads were at tile U-2,
// consumed by U-2's MMA (compiler lgkmcnt) before U-2's BAR — the issuing
// wave has crossed TWO barriers since. No same-window overwrite exists.  OK
// Tile U+1's reads are gated by U's vmcnt+BAR.                           OK
// vmcnt ledger (stream per tile: A(U+2),B(U+2)): at U's wait, outstanding
// = {A,B}(U+1), {A,B}(U+2) -> vmcnt(2) drains exactly tile U+1 (issued a
// full tile ago, ~1400 cyc flight — 2x r16's A depth). vmcnt(0) for
// U >= NKT-2 (no further issues).
// Swizzle: 16B chunk ^ ((row>>1)&3) (r9-r17: measured 0 conflicts).
// ---------------------------------------------------------------------------
__global__ __launch_bounds__(1024, 4) void gemm256_i8(
    const int8_t* __restrict__ XQ, const int8_t* __restrict__ QW,
    const float* __restrict__ XS, const float* __restrict__ scale,
    const float* __restrict__ bias, float* __restrict__ out) {
  __shared__ int8_t As[4][16384];  // 16 KB each buf (256 rows x 64 B)
  __shared__ int8_t Bs[4][16384];

  const int t = threadIdx.x;
  const int lane = t & 63;
  const int wid = t >> 6;
  const int wr = wid >> 2, wc = wid & 3;          // 4x4 wave grid
  const int m0 = blockIdx.x * 256;                // m fast-varying
  const int n0 = blockIdx.y * 256;

  const int8_t* ag = XQ + (size_t)m0 * DIN;
  const int8_t* bg = QW + (size_t)n0 * DIN;

  i32x4 acc[4][4] = {};            // [m-frag][n-frag], 64 AGPRs
  i32x4 a[4], b[4];

  const int r = lane & 15, kq = lane >> 4;        // frag row / 16B k-chunk
  const int srow = t >> 2;                        // staging row 0..255
  const int scol = ((t & 3) ^ ((srow >> 1) & 3)) * 16;  // inverse-swizzled src

#define ISSUE_A(Tt_, ab_) do {                                                  \
    const int T_ = (Tt_);                                                       \
    if (T_ < NKT)                                                               \
      glds16(ag + (size_t)srow * DIN + T_ * 64 + scol, &As[ab_][0] + t * 16);   \
  } while (0)

#define ISSUE_B(Tt_, bb_) do {                                                  \
    const int T_ = (Tt_);                                                       \
    if (T_ < NKT)                                                               \
      glds16(bg + (size_t)srow * DIN + T_ * 64 + scol, &Bs[bb_][0] + t * 16);   \
  } while (0)

#define READA(ab_) do {                                                         \
    _Pragma("unroll")                                                           \
    for (int mi = 0; mi < 4; ++mi) {                                            \
      const int row_ = wr * 64 + mi * 16 + r;                                   \
      a[mi] = *reinterpret_cast<const i32x4*>(                                  \
          &As[ab_][row_ * 64 + (kq ^ ((row_ >> 1) & 3)) * 16]);                 \
    }                                                                           \
  } while (0)

#define READB(bb_) do {                                                         \
    _Pragma("unroll")                                                           \
    for (int ni = 0; ni < 4; ++ni) {                                            \
      const int row_ = wc * 64 + ni * 16 + r;                                   \
      b[ni] = *reinterpret_cast<const i32x4*>(                                  \
          &Bs[bb_][row_ * 64 + (kq ^ ((row_ >> 1) & 3)) * 16]);                 \
    }                                                                           \
  } while (0)

// 16 MFMA: all 4 m-frags x all 4 n-frags
#define MMA16() do {                                                            \
    _Pragma("unroll")                                                           \
    for (int mi = 0; mi < 4; ++mi) {                                            \
      _Pragma("unroll")                                                         \
      for (int ni = 0; ni < 4; ++ni) {                                          \
        acc[mi][ni] = __builtin_amdgcn_mfma_i32_16x16x64_i8(                    \
            a[mi], b[ni], acc[mi][ni], 0, 0, 0);                                \
      }                                                                         \
    }                                                                           \
  } while (0)

#define BAR() __builtin_amdgcn_s_barrier()

#define TILE(T_, ab_) do {                                                      \
    READA(ab_);                                                                 \
    READB(ab_);                                                                 \
    ISSUE_A((T_) + 2, ((ab_) + 2) & 3);                                         \
    ISSUE_B((T_) + 2, ((ab_) + 2) & 3);                                         \
    MMA16();                                                                    \
    if ((T_) < NKT - 2)                                                         \
      asm volatile("s_waitcnt vmcnt(2)" ::: "memory");                          \
    else                                                                        \
      asm volatile("s_waitcnt vmcnt(0)" ::: "memory");                          \
    BAR();                                                                      \
  } while (0)

  // prologue: A(0),B(0),A(1),B(1) — stream order matches steady state.
  // vmcnt(2) => A(0),B(0) landed (tile 1 may remain in flight).
  ISSUE_A(0, 0); ISSUE_B(0, 0); ISSUE_A(1, 1); ISSUE_B(1, 1);
  asm volatile("s_waitcnt vmcnt(2)" ::: "memory");
  __builtin_amdgcn_s_barrier();

  for (int T = 0; T < NKT; T += 4) {
    TILE(T, 0);
    TILE(T + 1, 1);
    TILE(T + 2, 2);
    TILE(T + 3, 3);
  }

  // epilogue: C/D lane map col=lane&15, row=(lane>>4)*4+e (dtype-independent)
  const int q4 = lane >> 4;
#pragma unroll
  for (int ni = 0; ni < 4; ++ni) {
    const int col = n0 + wc * 64 + ni * 16 + r;
    const float sc = scale[col];
    const float bs = bias[col];
#pragma unroll
    for (int mi = 0; mi < 4; ++mi) {
      const int row = m0 + wr * 64 + mi * 16 + q4 * 4;
      const float4 xs4 = *reinterpret_cast<const float4*>(&XS[row]);
      out[(size_t)(row + 0) * DOUT + col] = (float)acc[mi][ni][0] * (xs4.x * sc) + bs;
      out[(size_t)(row + 1) * DOUT + col] = (float)acc[mi][ni][1] * (xs4.y * sc) + bs;
      out[(size_t)(row + 2) * DOUT + col] = (float)acc[mi][ni][2] * (xs4.z * sc) + bs;
      out[(size_t)(row + 3) * DOUT + col] = (float)acc[mi][ni][3] * (xs4.w * sc) + bs;
    }
  }
#undef ISSUE_A
#undef ISSUE_B
#undef READA
#undef READB
#undef MMA16
#undef BAR
#undef TILE
}

extern "C" void kernel_launch(void* const* d_in, const int* in_sizes, int n_in,
                              void* d_out, int out_size, void* d_ws, size_t ws_size,
                              hipStream_t stream) {
  const float* X     = (const float*)d_in[0];
  const float* W     = (const float*)d_in[1];
  const float* scale = (const float*)d_in[2];
  const float* bias  = (const float*)d_in[3];
  float* out = (float*)d_out;

  // ws layout: QW i8 16 MB | XQ i8 32 MB | XS fp32 32 KB
  int8_t* QW = (int8_t*)d_ws;
  int8_t* XQ = (int8_t*)d_ws + (size_t)DOUT * DIN;
  float*  XS = (float*)((int8_t*)d_ws + (size_t)DOUT * DIN + (size_t)MTOT * DIN);

  quant_fused<<<DOUT + MTOT, 256, 0, stream>>>(W, QW, X, XQ, XS);
  dim3 grid(MTOT / 256, DOUT / 256);
  gemm256_i8<<<grid, 1024, 0, stream>>>(XQ, QW, XS, scale, bias, out);
}

// Round 19
// 194.556 us; speedup vs baseline: 1.1029x; 1.1029x over previous
//
#include <hip/hip_runtime.h>
#include <hip/hip_bf16.h>
#include <stdint.h>

#define DIN   4096
#define DOUT  4096
#define MTOT  8192

#define BK    64
#define NKT   (DIN / BK)   // 64 K-tiles

typedef int i32x4 __attribute__((ext_vector_type(4)));

__device__ __forceinline__ void glds16(const void* g, void* l) {
  __builtin_amdgcn_global_load_lds(
      (__attribute__((address_space(1))) void*)g,
      (__attribute__((address_space(3))) void*)l, 16, 0, 0);
}

// ---------------------------------------------------------------------------
// Fused prep kernel (one launch, 12288 blocks):
//   blocks [0, DOUT):        per-row alpha (fp64) + ternary quantize W -> i8
//   blocks [DOUT, DOUT+MTOT): per-row max + quantize X -> i8, XS[row]
// Both paths are HBM-bound; fusing removes the serialization bubble between
// the two launches (independent work, full-device occupancy throughout).
// ---------------------------------------------------------------------------
__global__ __launch_bounds__(256) void quant_fused(
    const float* __restrict__ W, int8_t* __restrict__ QW,
    const float* __restrict__ X, int8_t* __restrict__ XQ,
    float* __restrict__ XS) {
  const int t = threadIdx.x;

  if (blockIdx.x < DOUT) {
    // ---- W path: ternary quantize with fp64-accumulated alpha ----
    const int row = blockIdx.x;
    const float* wr = W + (size_t)row * DIN;

    float4 v[4];
    double s = 0.0;
#pragma unroll
    for (int j = 0; j < 4; ++j) {
      v[j] = reinterpret_cast<const float4*>(wr)[j * 256 + t];
      s += (double)fabsf(v[j].x) + (double)fabsf(v[j].y) +
           (double)fabsf(v[j].z) + (double)fabsf(v[j].w);
    }
#pragma unroll
    for (int off = 32; off > 0; off >>= 1) s += __shfl_down(s, off, 64);

    __shared__ double ssum[4];
    __shared__ float salpha;
    if ((t & 63) == 0) ssum[t >> 6] = s;
    __syncthreads();
    if (t == 0)
      salpha = (float)((ssum[0] + ssum[1] + ssum[2] + ssum[3]) / (double)DIN);
    __syncthreads();
    const float alpha = salpha;

    int* qo = reinterpret_cast<int*>(QW + (size_t)row * DIN);
#pragma unroll
    for (int j = 0; j < 4; ++j) {
      int q0 = v[j].x > alpha ? 1 : (v[j].x < -alpha ? -1 : 0);
      int q1 = v[j].y > alpha ? 1 : (v[j].y < -alpha ? -1 : 0);
      int q2 = v[j].z > alpha ? 1 : (v[j].z < -alpha ? -1 : 0);
      int q3 = v[j].w > alpha ? 1 : (v[j].w < -alpha ? -1 : 0);
      qo[j * 256 + t] =
          (q0 & 0xff) | ((q1 & 0xff) << 8) | ((q2 & 0xff) << 16) | ((q3 & 0xff) << 24);
    }
  } else {
    // ---- X path: per-row absmax scale quantize ----
    const int row = blockIdx.x - DOUT;
    const float* xr = X + (size_t)row * DIN;

    float4 v[4];
    float mx = 0.f;
#pragma unroll
    for (int j = 0; j < 4; ++j) {
      v[j] = reinterpret_cast<const float4*>(xr)[j * 256 + t];
      mx = fmaxf(mx, fmaxf(fmaxf(fabsf(v[j].x), fabsf(v[j].y)),
                           fmaxf(fabsf(v[j].z), fabsf(v[j].w))));
    }
#pragma unroll
    for (int off = 32; off > 0; off >>= 1) mx = fmaxf(mx, __shfl_down(mx, off, 64));

    __shared__ float smax[4];
    __shared__ float sinv, ssc;
    if ((t & 63) == 0) smax[t >> 6] = mx;
    __syncthreads();
    if (t == 0) {
      float rm = fmaxf(fmaxf(smax[0], smax[1]), fmaxf(smax[2], smax[3]));
      sinv = rm > 0.f ? 127.f / rm : 0.f;
      ssc  = rm > 0.f ? rm / 127.f : 0.f;
    }
    __syncthreads();
    const float inv = sinv;
    if (t == 0) XS[row] = ssc;

    int* qo = reinterpret_cast<int*>(XQ + (size_t)row * DIN);
#pragma unroll
    for (int j = 0; j < 4; ++j) {
      int q0 = (int)rintf(v[j].x * inv);
      int q1 = (int)rintf(v[j].y * inv);
      int q2 = (int)rintf(v[j].z * inv);
      int q3 = (int)rintf(v[j].w * inv);
      qo[j * 256 + t] =
          (q0 & 0xff) | ((q1 & 0xff) << 8) | ((q2 & 0xff) << 16) | ((q3 & 0xff) << 24);
    }
  }
}

// ---------------------------------------------------------------------------
// GEMM kernel: r16/r17 best configuration (151.7 us measured).
// 256x256 i8 MFMA GEMM (mfma_i32_16x16x64_i8).
// Geometry: 1024 thr = 16 waves (4Mx4N), wave owns 64x64
// (acc = 16 x i32x4 = 64 AGPR, ~128 regs/wave -> 16 waves/CU).
// LDS: A/B [256 rows][64 B] i8 dbuf = 64 KB/block. One glds16/thread stages
// a whole 256x64 operand tile.
//
// 2 windows/tile (measured optimum: 8/4/2/1 windows -> 2 best; ph2 has
// zero ds_reads, so its MFMA cluster overlaps the next window's reads):
//   ph1: read a[4]+b[4] (8 ds_read); ISSUE A(T+1); MMA ni={0,1} (8); BAR
//   ph2: ISSUE B(T+2); MMA ni={2,3} (8); vmcnt(1|0); BAR
//
// Overwrite audit:
//   A(T+1)->As[buf^1]@ph1: As[buf^1] LDS reads were (T-1).ph1, consumed by
//     (T-1).ph1's MMA before its BAR; issuer crossed (T-1).ph2 BAR.     OK
//   B(T+2)->Bs[buf]@ph2: all Bs[buf] reads at T.ph1, consumed by T.ph1's
//     MMA before T.ph1's BAR; issue after.                              OK
//   Tile T+1 reads gated by T.ph2's vmcnt+BAR.                          OK
// vmcnt ledger (per-wave stream: ...B(T+1)@(T-1).ph2 < A(T+1)@T.ph1 <
//   B(T+2)@T.ph2, 1 instr each): at T.ph2 wait, vmcnt(1) => everything
//   through A(T+1) landed. vmcnt(0) for T >= NKT-2.
// Swizzle: 16B chunk ^ ((row>>1)&3) (measured 0 conflicts).
// ---------------------------------------------------------------------------
__global__ __launch_bounds__(1024, 4) void gemm256_i8(
    const int8_t* __restrict__ XQ, const int8_t* __restrict__ QW,
    const float* __restrict__ XS, const float* __restrict__ scale,
    const float* __restrict__ bias, float* __restrict__ out) {
  __shared__ int8_t As[2][16384];  // 16 KB each buf (256 rows x 64 B)
  __shared__ int8_t Bs[2][16384];

  const int t = threadIdx.x;
  const int lane = t & 63;
  const int wid = t >> 6;
  const int wr = wid >> 2, wc = wid & 3;          // 4x4 wave grid
  const int m0 = blockIdx.x * 256;                // m fast-varying
  const int n0 = blockIdx.y * 256;

  const int8_t* ag = XQ + (size_t)m0 * DIN;
  const int8_t* bg = QW + (size_t)n0 * DIN;

  i32x4 acc[4][4] = {};            // [m-frag][n-frag], 64 AGPRs
  i32x4 a[4], b[4];

  const int r = lane & 15, kq = lane >> 4;        // frag row / 16B k-chunk
  const int srow = t >> 2;                        // staging row 0..255
  const int scol = ((t & 3) ^ ((srow >> 1) & 3)) * 16;  // inverse-swizzled src

// stage one full 256x64 operand tile (1 glds16/thread)
#define ISSUE_T(Tt_, isb_) do {                                                 \
    const int T_ = (Tt_);                                                       \
    if (T_ < NKT) {                                                             \
      const int bf_ = T_ & 1;                                                   \
      const int8_t* gb_ = (isb_) ? bg : ag;                                     \
      int8_t* lb_ = (isb_) ? &Bs[bf_][0] : &As[bf_][0];                         \
      glds16(gb_ + (size_t)srow * DIN + T_ * 64 + scol, lb_ + t * 16);          \
    }                                                                           \
  } while (0)

#define READA(buf_) do {                                                        \
    _Pragma("unroll")                                                           \
    for (int mi = 0; mi < 4; ++mi) {                                            \
      const int row_ = wr * 64 + mi * 16 + r;                                   \
      a[mi] = *reinterpret_cast<const i32x4*>(                                  \
          &As[buf_][row_ * 64 + (kq ^ ((row_ >> 1) & 3)) * 16]);                \
    }                                                                           \
  } while (0)

#define READB(buf_) do {                                                        \
    _Pragma("unroll")                                                           \
    for (int ni = 0; ni < 4; ++ni) {                                            \
      const int row_ = wc * 64 + ni * 16 + r;                                   \
      b[ni] = *reinterpret_cast<const i32x4*>(                                  \
          &Bs[buf_][row_ * 64 + (kq ^ ((row_ >> 1) & 3)) * 16]);                \
    }                                                                           \
  } while (0)

// 8 MFMA: all 4 m-frags x n-frags {nh*2, nh*2+1}
#define MMA8(nh_) do {                                                          \
    _Pragma("unroll")                                                           \
    for (int mi = 0; mi < 4; ++mi) {                                            \
      _Pragma("unroll")                                                         \
      for (int ni = 0; ni < 2; ++ni) {                                          \
        acc[mi][(nh_) * 2 + ni] =                                               \
            __builtin_amdgcn_mfma_i32_16x16x64_i8(                              \
                a[mi], b[(nh_) * 2 + ni], acc[mi][(nh_) * 2 + ni], 0, 0, 0);    \
      }                                                                         \
    }                                                                           \
  } while (0)

#define BAR() __builtin_amdgcn_s_barrier()

#define TILE(T_, buf_) do {                                                     \
    /* ph1 — A(T+1) overwrite legal: As[buf^1] consumed at (T-1).ph1 */         \
    READA(buf_);                                                                \
    READB(buf_);                                                                \
    ISSUE_T((T_) + 1, 0);                                                       \
    MMA8(0);                                                                    \
    BAR();                                                                      \
    /* ph2 — B(T+2) overwrite legal: Bs[buf] consumed at T.ph1 */               \
    ISSUE_T((T_) + 2, 1);                                                       \
    MMA8(1);                                                                    \
    if ((T_) < NKT - 2)                                                         \
      asm volatile("s_waitcnt vmcnt(1)" ::: "memory");                          \
    else                                                                        \
      asm volatile("s_waitcnt vmcnt(0)" ::: "memory");                          \
    BAR();                                                                      \
  } while (0)

  // prologue: A(0), B(0), B(1) — 3 glds/thread, stream order matches steady
  // state. vmcnt(1) => A(0), B(0) landed (B(1) may remain in flight).
  ISSUE_T(0, 0); ISSUE_T(0, 1); ISSUE_T(1, 1);
  asm volatile("s_waitcnt vmcnt(1)" ::: "memory");
  __builtin_amdgcn_s_barrier();

  for (int T = 0; T < NKT; T += 2) {
    TILE(T, 0);
    TILE(T + 1, 1);
  }

  // epilogue: C/D lane map col=lane&15, row=(lane>>4)*4+e (dtype-independent)
  const int q4 = lane >> 4;
#pragma unroll
  for (int ni = 0; ni < 4; ++ni) {
    const int col = n0 + wc * 64 + ni * 16 + r;
    const float sc = scale[col];
    const float bs = bias[col];
#pragma unroll
    for (int mi = 0; mi < 4; ++mi) {
      const int row = m0 + wr * 64 + mi * 16 + q4 * 4;
      const float4 xs4 = *reinterpret_cast<const float4*>(&XS[row]);
      out[(size_t)(row + 0) * DOUT + col] = (float)acc[mi][ni][0] * (xs4.x * sc) + bs;
      out[(size_t)(row + 1) * DOUT + col] = (float)acc[mi][ni][1] * (xs4.y * sc) + bs;
      out[(size_t)(row + 2) * DOUT + col] = (float)acc[mi][ni][2] * (xs4.z * sc) + bs;
      out[(size_t)(row + 3) * DOUT + col] = (float)acc[mi][ni][3] * (xs4.w * sc) + bs;
    }
  }
#undef ISSUE_T
#undef READA
#undef READB
#undef MMA8
#undef BAR
#undef TILE
}

extern "C" void kernel_launch(void* const* d_in, const int* in_sizes, int n_in,
                              void* d_out, int out_size, void* d_ws, size_t ws_size,
                              hipStream_t stream) {
  const float* X     = (const float*)d_in[0];
  const float* W     = (const float*)d_in[1];
  const float* scale = (const float*)d_in[2];
  const float* bias  = (const float*)d_in[3];
  float* out = (float*)d_out;

  // ws layout: QW i8 16 MB | XQ i8 32 MB | XS fp32 32 KB
  int8_t* QW = (int8_t*)d_ws;
  int8_t* XQ = (int8_t*)d_ws + (size_t)DOUT * DIN;
  float*  XS = (float*)((int8_t*)d_ws + (size_t)DOUT * DIN + (size_t)MTOT * DIN);

  quant_fused<<<DOUT + MTOT, 256, 0, stream>>>(W, QW, X, XQ, XS);
  dim3 grid(MTOT / 256, DOUT / 256);
  gemm256_i8<<<grid, 1024, 0, stream>>>(XQ, QW, XS, scale, bias, out);
}